// Round 5
// baseline (399.839 us; speedup 1.0000x reference)
//
#include <hip/hip_runtime.h>

// MHA fused pipeline for MI355X (gfx950), f16 MFMA + fp32 accumulate.
// Round 12:
//  - gemm256: FULL-TILE-AHEAD staging. R8-R11 all measured ~135-137us
//    (MfmaUtil ~32, per-tile ~5140 cyc vs m201's 3300 at identical
//    geometry) regardless of phase schedule -> the ~1800cy/tile tax is
//    the P4 vmcnt waiting on loads issued only 0-2 phases earlier
//    (loaded-latency ~1500-2000cy; stall is schedule-invariant).
//    Now: during tile t stage tile t+2's half-tiles into buf (same
//    parity), each in the first phase after its region dies:
//    HA0+HB0@P2, HB1@P3, HA1@P4. vmcnt(8) at t.P4 then waits only on
//    loads 4-6 phases (~3300-5000cy) old -> free. Phases are otherwise
//    m201-exact: [reads | stages] BAR ; setprio(1) 16xMFMA setprio(0) ; BAR.
//  - attn: setprio around MFMA clusters (kept from R9).
//
// ws layout (bytes):
//   xh     @ 0          : 4096x2048 f16  (x cast)     [read by gemm256]
//   wqkvt  @ 16777216   : 6144x2048 f16  (Wqkv^T)    [dead after gemm256]
//   Oh     @ 16777216   : 4096x2048 f16  (attn out)   [overlays wqkvt]
//   Qh     @ 41943040   : [64 bh][2048][64] f16  (RoPE'd)
//   Kh     @ 58720256   : [64 bh][2048][64] f16  (RoPE'd)
//   Vth    @ 75497472   : [64 bh][64][2048] f16  (V^T)
//   woutt  @ 92274688   : 2048x2048 f16  (Wout^T)
//   total 100663296 B = 96 MB

typedef _Float16 half8 __attribute__((ext_vector_type(8)));
typedef _Float16 half4 __attribute__((ext_vector_type(4)));
typedef float floatx4 __attribute__((ext_vector_type(4)));

#define GLD_LDS16(gp, sp)                                        \
  __builtin_amdgcn_global_load_lds(                              \
      (__attribute__((address_space(1))) void*)(gp),             \
      (__attribute__((address_space(3))) void*)(sp), 16, 0, 0)

__device__ __forceinline__ floatx4 mfma16(half8 a, half8 b, floatx4 c) {
  return __builtin_amdgcn_mfma_f32_16x16x32_f16(a, b, c, 0, 0, 0);
}
__device__ __forceinline__ floatx4 mfma16k16(half4 a, half4 b, floatx4 c) {
  return __builtin_amdgcn_mfma_f32_16x16x16f16(a, b, c, 0, 0, 0);
}

// ---------------------------------------------------------------- cvt_x
__global__ __launch_bounds__(256) void cvt_x_kernel(const float* __restrict__ x,
                                                    _Float16* __restrict__ xh) {
  int idx = blockIdx.x * 256 + threadIdx.x;  // 8 elems each, 8.4M total
  const floatx4* p = (const floatx4*)x + (size_t)idx * 2;
  floatx4 a = p[0], b = p[1];
  half8 o;
#pragma unroll
  for (int j = 0; j < 4; ++j) { o[j] = (_Float16)a[j]; o[4 + j] = (_Float16)b[j]; }
  *((half8*)xh + idx) = o;
}

// ------------------------------------------------------- cvt + transpose W
// W (Kd x Nd) f32 row-major  ->  Wt (Nd x Kd) f16 row-major
__global__ __launch_bounds__(256) void cvt_wt_kernel(const float* __restrict__ W,
                                                     _Float16* __restrict__ Wt,
                                                     int Kd, int Nd) {
  __shared__ float tile[64][65];
  int n0 = blockIdx.x * 64, k0 = blockIdx.y * 64;
  int tid = threadIdx.x;
#pragma unroll
  for (int it = 0; it < 4; ++it) {
    int r = (tid >> 4) + it * 16;   // k-local
    int c = (tid & 15) * 4;         // n-local
    floatx4 v = *(const floatx4*)(W + (size_t)(k0 + r) * Nd + n0 + c);
    tile[r][c + 0] = v[0]; tile[r][c + 1] = v[1];
    tile[r][c + 2] = v[2]; tile[r][c + 3] = v[3];
  }
  __syncthreads();
#pragma unroll
  for (int it = 0; it < 2; ++it) {
    int r = (tid >> 3) + it * 32;   // n-local
    int c = (tid & 7) * 8;          // k-local
    half8 o;
#pragma unroll
    for (int j = 0; j < 8; ++j) o[j] = (_Float16)tile[c + j][r];
    *(half8*)(Wt + (size_t)(n0 + r) * Kd + k0 + c) = o;
  }
}

// ------------------------------------------------- 256x256 4-phase GEMM (QKV)
// C(256x256) = A(4096x2048) @ Bt(6144x2048)^T + bias, MODE-0 epilogue.
//
// 8 waves, wave (wr,wc) = (w>>2, w&3) owns a 128x64 output tile.
// LDS: sA/sB [2 buf][256 rows][64 cols] f16, 128 KiB total.
//   A LDS row = mh*128 + wr*64 + r   <-> global m-row  wr*128 + mh*64 + r
//   B LDS row = nh*128 + wc*32 + r   <-> global n-row  wc*64 + nh*32 + r
// Per-row XOR chunk swizzle via pre-swizzled GLOBAL source addresses; LDS
// destination linear (global_load_lds constraint).
//
// Phase p reads (quadrant pattern 12/4/8/0) feed phase p's 16 MFMA:
//   P1 (mh0,nh0): ld af<-mh0 (8), bf<-nh0 (4)
//   P2 (mh0,nh1): ld bf<-nh1 (4);  stage HA0(t+2), HB0(t+2)  [freed @P1]
//   P3 (mh1,nh1): ld af<-mh1 (8);  stage HB1(t+2)            [freed @P2]
//   P4 (mh1,nh0): (0 reads);       stage HA1(t+2)            [freed @P3]
//                 vmcnt(8 | 0 at tail)
// Each phase: [reads|stages] BAR ; setprio(1) MFMA x16 setprio(0) ; BAR.
// vmcnt(8)@t.P4 leaves tile t's 8 stage-loads in flight and retires tile
// t+1's 8 (issued during t-1, 4-6 phases old -> latency fully covered).
// Stages into the LIVE buf are safe: each targets a region whose last
// reader phase completed >=1 barrier before the stage issues (lockstep).
// Prologue: stage tile0+tile1 (16 loads), vmcnt(8) retires tile0.
// Tail (t+2>=NT): no stages; vmcnt(0) drains tile t+1's loads.
__global__ __launch_bounds__(512, 2) void gemm256_kernel(
    const _Float16* __restrict__ A, const _Float16* __restrict__ Bt,
    const float* __restrict__ bias,
    _Float16* __restrict__ Qd, _Float16* __restrict__ Kkd,
    _Float16* __restrict__ Vd) {
  __shared__ __align__(16) _Float16 sA[2][16384];
  __shared__ __align__(16) _Float16 sB[2][16384];
  constexpr int KD = 2048;
  constexpr int NT = KD / 64;  // 32 K-tiles

  int tid = threadIdx.x, w = tid >> 6, l = tid & 63;
  int lr = l & 15, quad = l >> 4;
  int wr = w >> 2, wc = w & 3;
  int m0 = blockIdx.y * 256, n0 = blockIdx.x * 256;

  // fragment-read swizzled column offsets (f16 units), loop-invariant
  int csw0 = ((quad) ^ (lr & 7)) * 8;
  int csw1 = ((quad + 4) ^ (lr & 7)) * 8;

  // staging source pointers: wave w, instr j covers LDS rows [(w*2+j)*8, +8)
  // of a half-tile; lane l -> row (w*2+j)*8 + (l>>3), chunk l&7. Global source
  // chunk is pre-swizzled: (l&7) ^ (l>>3).
  const _Float16* pA[2][2];
  const _Float16* pB[2][2];
  {
    int Rl0 = w * 16 + (l >> 3);
    int cs = ((l & 7) ^ (l >> 3)) * 8;
#pragma unroll
    for (int h = 0; h < 2; ++h) {
#pragma unroll
      for (int j = 0; j < 2; ++j) {
        int R = Rl0 + j * 8;                         // row within half [0,128)
        int rA = (R >> 6) * 128 + h * 64 + (R & 63); // global m-row offset
        int rB = ((R >> 5) & 3) * 64 + h * 32 + (R & 31);
        pA[h][j] = A + (size_t)(m0 + rA) * KD + cs;
        pB[h][j] = Bt + (size_t)(n0 + rB) * KD + cs;
      }
    }
  }

#define STAGE_A(BUF, H, KT)                                                  \
  GLD_LDS16(pA[H][0] + (KT), &sA[BUF][(H) * 8192 + (w * 2 + 0) * 512]);      \
  GLD_LDS16(pA[H][1] + (KT), &sA[BUF][(H) * 8192 + (w * 2 + 1) * 512]);
#define STAGE_B(BUF, H, KT)                                                  \
  GLD_LDS16(pB[H][0] + (KT), &sB[BUF][(H) * 8192 + (w * 2 + 0) * 512]);      \
  GLD_LDS16(pB[H][1] + (KT), &sB[BUF][(H) * 8192 + (w * 2 + 1) * 512]);

#define LDA(BUF, MH)                                                         \
  _Pragma("unroll") for (int i = 0; i < 4; ++i) {                            \
    int row_ = (MH) * 128 + wr * 64 + i * 16 + lr;                           \
    af[i][0] = *(const half8*)&sA[BUF][row_ * 64 + csw0];                    \
    af[i][1] = *(const half8*)&sA[BUF][row_ * 64 + csw1];                    \
  }
#define LDB(BUF, NH)                                                         \
  _Pragma("unroll") for (int j2 = 0; j2 < 2; ++j2) {                         \
    int row_ = (NH) * 128 + wc * 32 + j2 * 16 + lr;                          \
    bf[(NH) * 2 + j2][0] = *(const half8*)&sB[BUF][row_ * 64 + csw0];        \
    bf[(NH) * 2 + j2][1] = *(const half8*)&sB[BUF][row_ * 64 + csw1];        \
  }
#define MFMA_Q(MH, NH)                                                       \
  __builtin_amdgcn_s_setprio(1);                                             \
  _Pragma("unroll") for (int ks = 0; ks < 2; ++ks)                           \
  _Pragma("unroll") for (int i = 0; i < 4; ++i)                              \
  _Pragma("unroll") for (int jj = 0; jj < 2; ++jj)                           \
    acc[(MH) * 4 + i][(NH) * 2 + jj] = mfma16(                               \
        af[i][ks], bf[(NH) * 2 + jj][ks], acc[(MH) * 4 + i][(NH) * 2 + jj]); \
  __builtin_amdgcn_s_setprio(0);

  floatx4 z4 = {0.f, 0.f, 0.f, 0.f};
  floatx4 acc[8][4];
#pragma unroll
  for (int i = 0; i < 8; ++i)
#pragma unroll
    for (int j = 0; j < 4; ++j) acc[i][j] = z4;

  // prologue: tile0 (8 loads) then tile1 (8 loads); vmcnt(8) retires tile0.
  STAGE_A(0, 0, 0);
  STAGE_B(0, 0, 0);
  STAGE_B(0, 1, 0);
  STAGE_A(0, 1, 0);
  STAGE_A(1, 0, 64);
  STAGE_B(1, 0, 64);
  STAGE_B(1, 1, 64);
  STAGE_A(1, 1, 64);
  asm volatile("s_waitcnt vmcnt(8)" ::: "memory");
  __builtin_amdgcn_s_barrier();

  half8 af[4][2], bf[4][2];
#pragma unroll 2
  for (int t = 0; t < NT; ++t) {
    int buf = t & 1;
    int kt2 = (t + 2) * 64;
    // ---- P1 (mh0, nh0): 12 reads, no stage
    LDA(buf, 0);
    LDB(buf, 0);
    __builtin_amdgcn_s_barrier();
    MFMA_Q(0, 0);
    __builtin_amdgcn_s_barrier();
    // ---- P2 (mh0, nh1): 4 reads; stage HA0(t+2), HB0(t+2) [freed @P1]
    LDB(buf, 1);
    if (t + 2 < NT) { STAGE_A(buf, 0, kt2); STAGE_B(buf, 0, kt2); }
    __builtin_amdgcn_s_barrier();
    MFMA_Q(0, 1);
    __builtin_amdgcn_s_barrier();
    // ---- P3 (mh1, nh1): 8 reads; stage HB1(t+2) [freed @P2]
    LDA(buf, 1);
    if (t + 2 < NT) { STAGE_B(buf, 1, kt2); }
    __builtin_amdgcn_s_barrier();
    MFMA_Q(1, 1);
    __builtin_amdgcn_s_barrier();
    // ---- P4 (mh1, nh0): 0 reads; stage HA1(t+2) [freed @P3]; publish t+1
    if (t + 2 < NT) {
      STAGE_A(buf, 1, kt2);
      asm volatile("s_waitcnt vmcnt(8)" ::: "memory");
    } else {
      asm volatile("s_waitcnt vmcnt(0)" ::: "memory");
    }
    __builtin_amdgcn_s_barrier();
    MFMA_Q(1, 0);
    __builtin_amdgcn_s_barrier();
  }

  // epilogue. C/D layout: col = lane&15 (n within tile), row = quad*4 + r.
  // wave wc == head within this 256-col group; j-tiles give d = lr + j*16.
  int which = n0 >> 11;  // 0:q 1:k 2:v (256-col tile never straddles)
  float bj[4];
#pragma unroll
  for (int j = 0; j < 4; ++j) bj[j] = bias[n0 + wc * 64 + j * 16 + lr];
  int hh = ((n0 & 2047) >> 6) + wc;
  if (which == 2) {
    // V^T: acc[i][j][r] -> Vd[bh][d=j*16+lr][t..t+3], half4 runs
#pragma unroll
    for (int j = 0; j < 4; ++j) {
      int dd = j * 16 + lr;
#pragma unroll
      for (int i = 0; i < 8; ++i) {
        int m = m0 + wr * 128 + i * 16 + quad * 4;
        int bb = m >> 11, tt = m & 2047;
        half4 h;
#pragma unroll
        for (int r = 0; r < 4; ++r) h[r] = (_Float16)(acc[i][j][r] + bj[j]);
        *(half4*)&Vd[(((size_t)(bb * 32 + hh)) * 64 + dd) * 2048 + tt] = h;
      }
    }
  } else {
    _Float16* dst = which ? Kkd : Qd;
    // RoPE pair (d=lr, d=lr+16) = (acc[i][0], acc[i][1]); freq per lane
    float freq = __expf(-(float)lr * 0.57564627324851148f);  // 10000^(-lr/16)
#pragma unroll
    for (int i = 0; i < 8; ++i)
#pragma unroll
      for (int r = 0; r < 4; ++r) {
        int m = m0 + wr * 128 + i * 16 + quad * 4 + r;
        int bb = m >> 11, tt = m & 2047;
        float sn, cs2;
        __sincosf((float)tt * freq, &sn, &cs2);
        float x1 = acc[i][0][r] + bj[0];
        float x2 = acc[i][1][r] + bj[1];
        _Float16* row = dst + ((size_t)(bb * 32 + hh) * 2048 + (size_t)tt) * 64;
        row[lr] = (_Float16)(x1 * cs2 - x2 * sn);
        row[lr + 16] = (_Float16)(x1 * sn + x2 * cs2);
        row[lr + 32] = (_Float16)(acc[i][2][r] + bj[2]);
        row[lr + 48] = (_Float16)(acc[i][3][r] + bj[3]);
      }
  }
#undef STAGE_A
#undef STAGE_B
#undef LDA
#undef LDB
#undef MFMA_Q
}

// ---------------------------------------------------------------- GEMM 128^2
// (kept for the out-projection; 256^2 grid there would be 128 blocks = half
// the CUs idle.)
template <int MODE>
__global__ __launch_bounds__(256) void gemm_f16_kernel(
    const _Float16* __restrict__ A, const _Float16* __restrict__ Bt,
    const float* __restrict__ bias, int Kd, int Nd,
    _Float16* __restrict__ Qd, _Float16* __restrict__ Kkd,
    _Float16* __restrict__ Vd, float* __restrict__ Co) {
  __shared__ __align__(16) _Float16 sA[128 * 64];
  __shared__ __align__(16) _Float16 sB[128 * 64];
  int tid = threadIdx.x, w = tid >> 6, l = tid & 63;
  int lr = l & 15, lq = l >> 4;
  int m0 = blockIdx.y * 128, n0 = blockIdx.x * 128;
  int wrow = (w >> 1) * 64, wcol = (w & 1) * 64;

  floatx4 z4 = {0.f, 0.f, 0.f, 0.f};
  floatx4 acc[4][4];
#pragma unroll
  for (int i = 0; i < 4; ++i)
#pragma unroll
    for (int j = 0; j < 4; ++j) acc[i][j] = z4;

  int srow = l >> 3;              // row within 8-row chunk
  int slot = (l & 7) ^ srow;      // XOR-swizzled global k8-chunk
  const _Float16* aG = A + (size_t)(m0 + w * 32 + srow) * Kd + slot * 8;
  const _Float16* bG = Bt + (size_t)(n0 + w * 32 + srow) * Kd + slot * 8;
  _Float16* sAw = &sA[w * 2048];
  _Float16* sBw = &sB[w * 2048];

  for (int kt = 0; kt < Kd; kt += 64) {
#pragma unroll
    for (int t = 0; t < 4; ++t) {
      GLD_LDS16(aG + (size_t)t * 8 * Kd + kt, sAw + t * 512);
      GLD_LDS16(bG + (size_t)t * 8 * Kd + kt, sBw + t * 512);
    }
    __syncthreads();
#pragma unroll
    for (int ks = 0; ks < 2; ++ks) {
      half8 af[4], bf[4];
#pragma unroll
      for (int i = 0; i < 4; ++i) {
        int ar = wrow + i * 16 + lr;
        int br = wcol + i * 16 + lr;
        int sl = (((ks << 2) | lq) ^ (lr & 7)) * 8;
        af[i] = *(const half8*)&sA[ar * 64 + sl];
        bf[i] = *(const half8*)&sB[br * 64 + sl];
      }
#pragma unroll
      for (int i = 0; i < 4; ++i)
#pragma unroll
        for (int j = 0; j < 4; ++j) acc[i][j] = mfma16(af[i], bf[j], acc[i][j]);
    }
    __syncthreads();
  }

  if (MODE == 0) {
    // (unused in this round's launch; retained for completeness)
    int which = n0 >> 11;
    float bj[4];
#pragma unroll
    for (int j = 0; j < 4; ++j) bj[j] = bias[n0 + wcol + j * 16 + lr];
    int hh = ((n0 & 2047) + wcol) >> 6;
    if (which == 2) {
#pragma unroll
      for (int j = 0; j < 4; ++j) {
        int dd = j * 16 + lr;
#pragma unroll
        for (int i = 0; i < 4; ++i) {
          int m = m0 + wrow + i * 16 + lq * 4;
          int bb = m >> 11, t = m & 2047;
          half4 h;
#pragma unroll
          for (int r = 0; r < 4; ++r) h[r] = (_Float16)(acc[i][j][r] + bj[j]);
          *(half4*)&Vd[(((size_t)(bb * 32 + hh)) * 64 + dd) * 2048 + t] = h;
        }
      }
    } else {
      _Float16* dst = which ? Kkd : Qd;
      float freq = __expf(-(float)lr * 0.57564627324851148f);
#pragma unroll
      for (int i = 0; i < 4; ++i)
#pragma unroll
        for (int r = 0; r < 4; ++r) {
          int m = m0 + wrow + i * 16 + lq * 4 + r;
          int bb = m >> 11, t = m & 2047;
          float sn, cs;
          __sincosf((float)t * freq, &sn, &cs);
          float x1 = acc[i][0][r] + bj[0];
          float x2 = acc[i][1][r] + bj[1];
          _Float16* row = dst + ((size_t)(bb * 32 + hh) * 2048 + (size_t)t) * 64;
          row[lr]      = (_Float16)(x1 * cs - x2 * sn);
          row[lr + 16] = (_Float16)(x1 * sn + x2 * cs);
          row[lr + 32] = (_Float16)(acc[i][2][r] + bj[2]);
          row[lr + 48] = (_Float16)(acc[i][3][r] + bj[3]);
        }
    }
  } else {
#pragma unroll
    for (int j = 0; j < 4; ++j) {
      int n = n0 + wcol + j * 16 + lr;
      float bj = bias[n];
#pragma unroll
      for (int i = 0; i < 4; ++i)
#pragma unroll
        for (int r = 0; r < 4; ++r) {
          int m = m0 + wrow + i * 16 + lq * 4 + r;
          Co[(size_t)m * Nd + n] = acc[i][j][r] + bj;
        }
    }
  }
}

// ---------------------------------------------------------------- attention
// Flash-style causal attention, S^T formulation + register prefetch +
// PAIRED q-tiles: block (bh, by) runs qt=15-by then qt=by -> every block
// does exactly 17 kv-iterations (uniform work, no imbalance tail).
__global__ __launch_bounds__(256) void attn_kernel(
    const _Float16* __restrict__ Q, const _Float16* __restrict__ Kk,
    const _Float16* __restrict__ Vt, _Float16* __restrict__ O) {
  constexpr int S = 2048;
  int bh = blockIdx.x;
  int by = blockIdx.y;  // 0..7
  int bb = bh >> 5, hh = bh & 31;
  const _Float16* Qb = Q + (size_t)bh * S * 64;
  const _Float16* Kb = Kk + (size_t)bh * S * 64;
  const _Float16* Vb = Vt + (size_t)bh * 64 * S;

  __shared__ __align__(16) _Float16 sK[128 * 72];   // [kv][64+pad], reused as sO
  __shared__ __align__(16) _Float16 sVt[64 * 136];  // [d][128+pad]

  int tid = threadIdx.x, w = tid >> 6, l = tid & 63;
  int lr = l & 15, quad = l >> 4;

  int rk = tid >> 3, ck = (tid & 7) * 8;   // K: 32 rows x 64d per pass
  int rv = tid >> 4, cv = (tid & 15) * 8;  // Vt: 16 rows x 128kv per pass
  const _Float16* Kst = Kb + (size_t)rk * 64 + ck;
  const _Float16* Vst = Vb + (size_t)rv * S + cv;

  int qts[2] = {15 - by, by};
  floatx4 z4 = {0.f, 0.f, 0.f, 0.f};

  for (int h = 0; h < 2; ++h) {
    int qt = qts[h];
    int q0 = qt * 128;

    half8 qf[2][2];  // [qtile][ks]
#pragma unroll
    for (int qtl = 0; qtl < 2; ++qtl)
#pragma unroll
      for (int ks = 0; ks < 2; ++ks) {
        half8 v = *(const half8*)(Qb + (size_t)(q0 + w * 32 + qtl * 16 + lr) * 64 +
                                  ks * 32 + quad * 8);
        qf[qtl][ks] = v * (_Float16)0.18033688f;  // 0.125 * log2(e)
      }

    floatx4 Oa[4][2];
    float m_i[2] = {-1e30f, -1e30f}, l_i[2] = {0.f, 0.f};
#pragma unroll
    for (int dt = 0; dt < 4; ++dt)
#pragma unroll
      for (int qtl = 0; qtl < 2; ++qtl) Oa[dt][qtl] = z4;

    half8 kpre[4], vpre[4];
#pragma unroll
    for (int it = 0; it < 4; ++it) {
      kpre[it] = *(const half8*)(Kst + (size_t)it * 32 * 64);
      vpre[it] = *(const half8*)(Vst + (size_t)it * 16 * S);
    }

    for (int jt = 0; jt <= qt; ++jt) {
#pragma unroll
      for (int it = 0; it < 4; ++it) {
        *(half8*)&sK[(rk + it * 32) * 72 + ck] = kpre[it];
        *(half8*)&sVt[(rv + it * 16) * 136 + cv] = vpre[it];
      }
      if (jt < qt) {
        int kv1 = (jt + 1) * 128;
#pragma unroll
        for (int it = 0; it < 4; ++it) {
          kpre[it] = *(const half8*)(Kst + (size_t)(kv1 + it * 32) * 64);
          vpre[it] = *(const half8*)(Vst + kv1 + (size_t)it * 16 * S);
        }
      }
      __syncthreads();

      floatx4 Sa[2][8];
#pragma unroll
      for (int qtl = 0; qtl < 2; ++qtl)
#pragma unroll
        for (int kvt = 0; kvt < 8; ++kvt) Sa[qtl][kvt] = z4;
      __builtin_amdgcn_s_setprio(1);
#pragma unroll
      for (int ks = 0; ks < 2; ++ks) {
#pragma unroll
        for (int kvt = 0; kvt < 8; ++kvt) {
          half8 kf = *(const half8*)&sK[(kvt * 16 + lr) * 72 + ks * 32 + quad * 8];
          Sa[0][kvt] = mfma16(kf, qf[0][ks], Sa[0][kvt]);
          Sa[1][kvt] = mfma16(kf, qf[1][ks], Sa[1][kvt]);
        }
      }
      __builtin_amdgcn_s_setprio(0);

      if (jt == qt) {
#pragma unroll
        for (int qtl = 0; qtl < 2; ++qtl) {
          int q_loc = w * 32 + qtl * 16 + lr;
#pragma unroll
          for (int kvt = 0; kvt < 8; ++kvt) {
            int kv_base = kvt * 16 + quad * 4;
#pragma unroll
            for (int r = 0; r < 4; ++r)
              if (kv_base + r > q_loc) Sa[qtl][kvt][r] = -1e30f;
          }
        }
      }

#pragma unroll
      for (int qtl = 0; qtl < 2; ++qtl) {
        float mx = Sa[qtl][0][0];
#pragma unroll
        for (int kvt = 0; kvt < 8; ++kvt)
#pragma unroll
          for (int r = 0; r < 4; ++r) mx = fmaxf(mx, Sa[qtl][kvt][r]);
        mx = fmaxf(mx, __shfl_xor(mx, 16));
        mx = fmaxf(mx, __shfl_xor(mx, 32));
        float mnew = fmaxf(m_i[qtl], mx);
        float alpha = __builtin_amdgcn_exp2f(m_i[qtl] - mnew);
        m_i[qtl] = mnew;
        float rs = 0.f;
#pragma unroll
        for (int kvt = 0; kvt < 8; ++kvt)
#pragma unroll
          for (int r = 0; r < 4; ++r) {
            float p = __builtin_amdgcn_exp2f(Sa[qtl][kvt][r] - mnew);
            Sa[qtl][kvt][r] = p;
            rs += p;
          }
        rs += __shfl_xor(rs, 16);
        rs += __shfl_xor(rs, 32);
        l_i[qtl] = l_i[qtl] * alpha + rs;
#pragma unroll
        for (int dt = 0; dt < 4; ++dt) Oa[dt][qtl] *= alpha;
      }

      __builtin_amdgcn_s_setprio(1);
#pragma unroll
      for (int kvt = 0; kvt < 8; ++kvt) {
        half4 vf[4];
#pragma unroll
        for (int dt = 0; dt < 4; ++dt)
          vf[dt] = *(const half4*)&sVt[(dt * 16 + lr) * 136 + kvt * 16 + quad * 4];
        half4 pf[2];
#pragma unroll
        for (int qtl = 0; qtl < 2; ++qtl) {
          pf[qtl][0] = (_Float16)Sa[qtl][kvt][0];
          pf[qtl][1] = (_Float16)Sa[qtl][kvt][1];
          pf[qtl][2] = (_Float16)Sa[qtl][kvt][2];
          pf[qtl][3] = (_Float16)Sa[qtl][kvt][3];
        }
#pragma unroll
        for (int dt = 0; dt < 4; ++dt)
#pragma unroll
          for (int qtl = 0; qtl < 2; ++qtl)
            Oa[dt][qtl] = mfma16k16(vf[dt], pf[qtl], Oa[dt][qtl]);
      }
      __builtin_amdgcn_s_setprio(0);
      __syncthreads();
    }

    float inv0 = 1.0f / l_i[0], inv1 = 1.0f / l_i[1];
#pragma unroll
    for (int dt = 0; dt < 4; ++dt)
#pragma unroll
      for (int qtl = 0; qtl < 2; ++qtl) {
        float inv = qtl ? inv1 : inv0;
        floatx4 o = Oa[dt][qtl];
        half4 hv;
        hv[0] = (_Float16)(o[0] * inv); hv[1] = (_Float16)(o[1] * inv);
        hv[2] = (_Float16)(o[2] * inv); hv[3] = (_Float16)(o[3] * inv);
        *(half4*)&sK[(w * 32 + qtl * 16 + lr) * 72 + dt * 16 + quad * 4] = hv;
      }
    __syncthreads();
#pragma unroll
    for (int it = 0; it < 2; ++it) {
      int row = (tid >> 2) + it * 64;
      int t = q0 + row;
      _Float16* orow = O + ((size_t)(bb * 2048 + t)) * 2048 + hh * 64;
#pragma unroll
      for (int cc = 0; cc < 2; ++cc) {
        int col = (tid & 3) * 16 + cc * 8;
        *(half8*)(orow + col) = *(const half8*)&sK[row * 72 + col];
      }
    }
    __syncthreads();
  }
}

// ---------------------------------------------------------------- launch
extern "C" void kernel_launch(void* const* d_in, const int* in_sizes, int n_in,
                              void* d_out, int out_size, void* d_ws, size_t ws_size,
                              hipStream_t stream) {
  (void)in_sizes; (void)n_in; (void)out_size; (void)ws_size;
  const float* x = (const float*)d_in[0];
  const float* Wqkv = (const float*)d_in[1];
  const float* bqkv = (const float*)d_in[2];
  const float* Wout = (const float*)d_in[3];
  const float* bout = (const float*)d_in[4];
  float* out = (float*)d_out;
  char* ws = (char*)d_ws;

  _Float16* xh    = (_Float16*)(ws + 0);
  _Float16* wqkvt = (_Float16*)(ws + 16777216);
  _Float16* Oh    = (_Float16*)(ws + 16777216);   // overlays wqkvt (dead)
  _Float16* Qh    = (_Float16*)(ws + 41943040);
  _Float16* Kh    = (_Float16*)(ws + 58720256);
  _Float16* Vth   = (_Float16*)(ws + 75497472);   // V^T
  _Float16* woutt = (_Float16*)(ws + 92274688);   // total 96 MB

  cvt_x_kernel<<<4096, 256, 0, stream>>>(x, xh);
  cvt_wt_kernel<<<dim3(96, 32), 256, 0, stream>>>(Wqkv, wqkvt, 2048, 6144);
  cvt_wt_kernel<<<dim3(32, 32), 256, 0, stream>>>(Wout, woutt, 2048, 2048);
  gemm256_kernel<<<dim3(24, 16), 512, 0, stream>>>(xh, wqkvt, bqkv, Qh, Kh, Vth);
  attn_kernel<<<dim3(64, 8), 256, 0, stream>>>(Qh, Kh, Vth, Oh);
  gemm_f16_kernel<1><<<dim3(16, 32), 256, 0, stream>>>(
      Oh, woutt, bout, 2048, 2048, nullptr, nullptr, nullptr, out);
}

// Round 6
// 395.707 us; speedup vs baseline: 1.0104x; 1.0104x over previous
//
#include <hip/hip_runtime.h>

// MHA fused pipeline for MI355X (gfx950), f16 MFMA + fp32 accumulate.
// Round 13:
//  - gemm256: ONE barrier per K-tile. R8/R9/R10/R12 (2-bar, 1-bar-per-phase,
//    m-pair regs, full-tile-ahead vmcnt) all measured 134-137us with
//    MfmaUtil~32 and per-tile 5025cy == LDS 2304 + MFMA 2483 fully serial.
//    Schedule-invariance => the 4-8 intra-tile barriers re-align all 8
//    waves each phase: everyone reads together (matrix pipe idle), then
//    everyone MFMAs together (LDS idle). Intra-tile barriers are not needed
//    for correctness (each wave reads its own frags from buf; stages target
//    nbuf which nobody reads this tile). New loop: stage t+1 at top, m-pair
//    register pipeline with NO interior barriers, vmcnt(0)+s_barrier once
//    at tile end. Waves drift within the tile -> cross-wave LDS||MFMA
//    overlap; setprio now has role diversity to arbitrate.
//    Hazards: buf reads published by prev tile's vmcnt+barrier; nbuf stages
//    ordered after end-of-(t-1) barrier (its readers were tile t-1); skew
//    bounded by the per-tile barrier; tail has 0 outstanding loads.
//  - attn: setprio around MFMA clusters (kept).
//
// ws layout (bytes):
//   xh     @ 0          : 4096x2048 f16  (x cast)     [read by gemm256]
//   wqkvt  @ 16777216   : 6144x2048 f16  (Wqkv^T)    [dead after gemm256]
//   Oh     @ 16777216   : 4096x2048 f16  (attn out)   [overlays wqkvt]
//   Qh     @ 41943040   : [64 bh][2048][64] f16  (RoPE'd)
//   Kh     @ 58720256   : [64 bh][2048][64] f16  (RoPE'd)
//   Vth    @ 75497472   : [64 bh][64][2048] f16  (V^T)
//   woutt  @ 92274688   : 2048x2048 f16  (Wout^T)
//   total 100663296 B = 96 MB

typedef _Float16 half8 __attribute__((ext_vector_type(8)));
typedef _Float16 half4 __attribute__((ext_vector_type(4)));
typedef float floatx4 __attribute__((ext_vector_type(4)));

#define GLD_LDS16(gp, sp)                                        \
  __builtin_amdgcn_global_load_lds(                              \
      (__attribute__((address_space(1))) void*)(gp),             \
      (__attribute__((address_space(3))) void*)(sp), 16, 0, 0)

__device__ __forceinline__ floatx4 mfma16(half8 a, half8 b, floatx4 c) {
  return __builtin_amdgcn_mfma_f32_16x16x32_f16(a, b, c, 0, 0, 0);
}
__device__ __forceinline__ floatx4 mfma16k16(half4 a, half4 b, floatx4 c) {
  return __builtin_amdgcn_mfma_f32_16x16x16f16(a, b, c, 0, 0, 0);
}

// ---------------------------------------------------------------- cvt_x
__global__ __launch_bounds__(256) void cvt_x_kernel(const float* __restrict__ x,
                                                    _Float16* __restrict__ xh) {
  int idx = blockIdx.x * 256 + threadIdx.x;  // 8 elems each, 8.4M total
  const floatx4* p = (const floatx4*)x + (size_t)idx * 2;
  floatx4 a = p[0], b = p[1];
  half8 o;
#pragma unroll
  for (int j = 0; j < 4; ++j) { o[j] = (_Float16)a[j]; o[4 + j] = (_Float16)b[j]; }
  *((half8*)xh + idx) = o;
}

// ------------------------------------------------------- cvt + transpose W
// W (Kd x Nd) f32 row-major  ->  Wt (Nd x Kd) f16 row-major
__global__ __launch_bounds__(256) void cvt_wt_kernel(const float* __restrict__ W,
                                                     _Float16* __restrict__ Wt,
                                                     int Kd, int Nd) {
  __shared__ float tile[64][65];
  int n0 = blockIdx.x * 64, k0 = blockIdx.y * 64;
  int tid = threadIdx.x;
#pragma unroll
  for (int it = 0; it < 4; ++it) {
    int r = (tid >> 4) + it * 16;   // k-local
    int c = (tid & 15) * 4;         // n-local
    floatx4 v = *(const floatx4*)(W + (size_t)(k0 + r) * Nd + n0 + c);
    tile[r][c + 0] = v[0]; tile[r][c + 1] = v[1];
    tile[r][c + 2] = v[2]; tile[r][c + 3] = v[3];
  }
  __syncthreads();
#pragma unroll
  for (int it = 0; it < 2; ++it) {
    int r = (tid >> 3) + it * 32;   // n-local
    int c = (tid & 7) * 8;          // k-local
    half8 o;
#pragma unroll
    for (int j = 0; j < 8; ++j) o[j] = (_Float16)tile[c + j][r];
    *(half8*)(Wt + (size_t)(n0 + r) * Kd + k0 + c) = o;
  }
}

// ------------------------------------------- 256x256 1-barrier GEMM (QKV)
// C(256x256) = A(4096x2048) @ Bt(6144x2048)^T + bias, MODE-0 epilogue.
//
// 8 waves, wave (wr,wc) = (w>>2, w&3) owns a 128x64 output tile.
// LDS: sA/sB [2 buf][256 rows][64 cols] f16, 128 KiB total.
//   A LDS row = mh*128 + wr*64 + r   <-> global m-row  wr*128 + mh*64 + r
//   B LDS row = nh*128 + wc*32 + r   <-> global n-row  wc*64 + nh*32 + r
// Per-row XOR chunk swizzle via pre-swizzled GLOBAL source addresses; LDS
// destination linear (global_load_lds constraint).
//
// Per tile t (per wave, NO interior barriers):
//   STAGE t+1 -> nbuf (16 gld_lds, oldest in vmcnt queue)
//   LDBH(0); LDBH(1)            // bf: 8 ds_read_b128
//   LDAP(afA, p0)               // 4 reads
//   LDAP(afB, p1); MFMA p0(afA) // reads of p+1 overlap MFMA of p
//   LDAP(afA, p2); MFMA p1(afB)
//   LDAP(afB, p3); MFMA p2(afA)
//                  MFMA p3(afB)
//   vmcnt(0)  (t+1's stages, issued a full tile ago -> covered)
//   s_barrier (publishes nbuf; bounds skew to one tile)
__global__ __launch_bounds__(512, 2) void gemm256_kernel(
    const _Float16* __restrict__ A, const _Float16* __restrict__ Bt,
    const float* __restrict__ bias,
    _Float16* __restrict__ Qd, _Float16* __restrict__ Kkd,
    _Float16* __restrict__ Vd) {
  __shared__ __align__(16) _Float16 sA[2][16384];
  __shared__ __align__(16) _Float16 sB[2][16384];
  constexpr int KD = 2048;
  constexpr int NT = KD / 64;  // 32 K-tiles

  int tid = threadIdx.x, w = tid >> 6, l = tid & 63;
  int lr = l & 15, quad = l >> 4;
  int wr = w >> 2, wc = w & 3;
  int m0 = blockIdx.y * 256, n0 = blockIdx.x * 256;

  // fragment-read swizzled column offsets (f16 units), loop-invariant
  int csw0 = ((quad) ^ (lr & 7)) * 8;
  int csw1 = ((quad + 4) ^ (lr & 7)) * 8;

  // staging source pointers: wave w, instr j covers LDS rows [(w*2+j)*8, +8)
  // of a half-tile; lane l -> row (w*2+j)*8 + (l>>3), chunk l&7. Global source
  // chunk is pre-swizzled: (l&7) ^ (l>>3).
  const _Float16* pA[2][2];
  const _Float16* pB[2][2];
  {
    int Rl0 = w * 16 + (l >> 3);
    int cs = ((l & 7) ^ (l >> 3)) * 8;
#pragma unroll
    for (int h = 0; h < 2; ++h) {
#pragma unroll
      for (int j = 0; j < 2; ++j) {
        int R = Rl0 + j * 8;                         // row within half [0,128)
        int rA = (R >> 6) * 128 + h * 64 + (R & 63); // global m-row offset
        int rB = ((R >> 5) & 3) * 64 + h * 32 + (R & 31);
        pA[h][j] = A + (size_t)(m0 + rA) * KD + cs;
        pB[h][j] = Bt + (size_t)(n0 + rB) * KD + cs;
      }
    }
  }

#define STAGE_A(BUF, H, KT)                                                  \
  GLD_LDS16(pA[H][0] + (KT), &sA[BUF][(H) * 8192 + (w * 2 + 0) * 512]);      \
  GLD_LDS16(pA[H][1] + (KT), &sA[BUF][(H) * 8192 + (w * 2 + 1) * 512]);
#define STAGE_B(BUF, H, KT)                                                  \
  GLD_LDS16(pB[H][0] + (KT), &sB[BUF][(H) * 8192 + (w * 2 + 0) * 512]);      \
  GLD_LDS16(pB[H][1] + (KT), &sB[BUF][(H) * 8192 + (w * 2 + 1) * 512]);

// load A fragment pair P (rows 2P,2P+1 of the wave's 8) into set AF
#define LDAP(AF, BUF, P)                                                     \
  _Pragma("unroll") for (int i = 0; i < 2; ++i) {                            \
    int row_ = ((P) >> 1) * 128 + wr * 64 + (((P) & 1) * 2 + i) * 16 + lr;   \
    AF[i][0] = *(const half8*)&sA[BUF][row_ * 64 + csw0];                    \
    AF[i][1] = *(const half8*)&sA[BUF][row_ * 64 + csw1];                    \
  }
// load B fragment half NH (2 n-rows) into bf[NH*2 .. NH*2+1]
#define LDBH(NH, BUF)                                                        \
  _Pragma("unroll") for (int j2 = 0; j2 < 2; ++j2) {                         \
    int row_ = (NH) * 128 + wc * 32 + j2 * 16 + lr;                          \
    bf[(NH) * 2 + j2][0] = *(const half8*)&sB[BUF][row_ * 64 + csw0];        \
    bf[(NH) * 2 + j2][1] = *(const half8*)&sB[BUF][row_ * 64 + csw1];        \
  }
// 16 MFMA for m-pair P using A-set AF
#define MFMA_P(P, AF)                                                        \
  __builtin_amdgcn_s_setprio(1);                                             \
  _Pragma("unroll") for (int j = 0; j < 4; ++j)                              \
  _Pragma("unroll") for (int ks = 0; ks < 2; ++ks)                           \
  _Pragma("unroll") for (int i = 0; i < 2; ++i)                              \
    acc[2 * (P) + i][j] = mfma16(AF[i][ks], bf[j][ks], acc[2 * (P) + i][j]); \
  __builtin_amdgcn_s_setprio(0);

  floatx4 z4 = {0.f, 0.f, 0.f, 0.f};
  floatx4 acc[8][4];
#pragma unroll
  for (int i = 0; i < 8; ++i)
#pragma unroll
    for (int j = 0; j < 4; ++j) acc[i][j] = z4;

  // prologue: tile0 -> buf0 (8 loads), drain, barrier.
  STAGE_A(0, 0, 0);
  STAGE_B(0, 0, 0);
  STAGE_B(0, 1, 0);
  STAGE_A(0, 1, 0);
  asm volatile("s_waitcnt vmcnt(0)" ::: "memory");
  __builtin_amdgcn_s_barrier();

  half8 afA[2][2], afB[2][2], bf[4][2];
#pragma unroll 2
  for (int t = 0; t < NT; ++t) {
    int buf = t & 1, nbuf = buf ^ 1;
    int kt1 = (t + 1) * 64;
    // stage next tile first (oldest in queue; HBM latency hides under tile)
    if (t + 1 < NT) {
      STAGE_A(nbuf, 0, kt1);
      STAGE_B(nbuf, 0, kt1);
      STAGE_B(nbuf, 1, kt1);
      STAGE_A(nbuf, 1, kt1);
    }
    // register-pipelined m-pairs, no interior barriers
    LDBH(0, buf);
    LDBH(1, buf);
    LDAP(afA, buf, 0);
    LDAP(afB, buf, 1);
    MFMA_P(0, afA);
    LDAP(afA, buf, 2);
    MFMA_P(1, afB);
    LDAP(afB, buf, 3);
    MFMA_P(2, afA);
    MFMA_P(3, afB);
    // publish tile t+1 (loads issued a full tile ago) and bound skew
    asm volatile("s_waitcnt vmcnt(0)" ::: "memory");
    __builtin_amdgcn_s_barrier();
  }

  // epilogue. C/D layout: col = lane&15 (n within tile), row = quad*4 + r.
  // acc[f][j] <-> global m-row wr*128 + f*16 + quad*4 + r  (f = 2P+i).
  int which = n0 >> 11;  // 0:q 1:k 2:v (256-col tile never straddles)
  float bj[4];
#pragma unroll
  for (int j = 0; j < 4; ++j) bj[j] = bias[n0 + wc * 64 + j * 16 + lr];
  int hh = ((n0 & 2047) >> 6) + wc;
  if (which == 2) {
    // V^T: acc[i][j][r] -> Vd[bh][d=j*16+lr][t..t+3], half4 runs
#pragma unroll
    for (int j = 0; j < 4; ++j) {
      int dd = j * 16 + lr;
#pragma unroll
      for (int i = 0; i < 8; ++i) {
        int m = m0 + wr * 128 + i * 16 + quad * 4;
        int bb = m >> 11, tt = m & 2047;
        half4 h;
#pragma unroll
        for (int r = 0; r < 4; ++r) h[r] = (_Float16)(acc[i][j][r] + bj[j]);
        *(half4*)&Vd[(((size_t)(bb * 32 + hh)) * 64 + dd) * 2048 + tt] = h;
      }
    }
  } else {
    _Float16* dst = which ? Kkd : Qd;
    // RoPE pair (d=lr, d=lr+16) = (acc[i][0], acc[i][1]); freq per lane
    float freq = __expf(-(float)lr * 0.57564627324851148f);  // 10000^(-lr/16)
#pragma unroll
    for (int i = 0; i < 8; ++i)
#pragma unroll
      for (int r = 0; r < 4; ++r) {
        int m = m0 + wr * 128 + i * 16 + quad * 4 + r;
        int bb = m >> 11, tt = m & 2047;
        float sn, cs2;
        __sincosf((float)tt * freq, &sn, &cs2);
        float x1 = acc[i][0][r] + bj[0];
        float x2 = acc[i][1][r] + bj[1];
        _Float16* row = dst + ((size_t)(bb * 32 + hh) * 2048 + (size_t)tt) * 64;
        row[lr] = (_Float16)(x1 * cs2 - x2 * sn);
        row[lr + 16] = (_Float16)(x1 * sn + x2 * cs2);
        row[lr + 32] = (_Float16)(acc[i][2][r] + bj[2]);
        row[lr + 48] = (_Float16)(acc[i][3][r] + bj[3]);
      }
  }
#undef STAGE_A
#undef STAGE_B
#undef LDAP
#undef LDBH
#undef MFMA_P
}

// ---------------------------------------------------------------- GEMM 128^2
// (kept for the out-projection; 256^2 grid there would be 128 blocks = half
// the CUs idle.)
template <int MODE>
__global__ __launch_bounds__(256) void gemm_f16_kernel(
    const _Float16* __restrict__ A, const _Float16* __restrict__ Bt,
    const float* __restrict__ bias, int Kd, int Nd,
    _Float16* __restrict__ Qd, _Float16* __restrict__ Kkd,
    _Float16* __restrict__ Vd, float* __restrict__ Co) {
  __shared__ __align__(16) _Float16 sA[128 * 64];
  __shared__ __align__(16) _Float16 sB[128 * 64];
  int tid = threadIdx.x, w = tid >> 6, l = tid & 63;
  int lr = l & 15, lq = l >> 4;
  int m0 = blockIdx.y * 128, n0 = blockIdx.x * 128;
  int wrow = (w >> 1) * 64, wcol = (w & 1) * 64;

  floatx4 z4 = {0.f, 0.f, 0.f, 0.f};
  floatx4 acc[4][4];
#pragma unroll
  for (int i = 0; i < 4; ++i)
#pragma unroll
    for (int j = 0; j < 4; ++j) acc[i][j] = z4;

  int srow = l >> 3;              // row within 8-row chunk
  int slot = (l & 7) ^ srow;      // XOR-swizzled global k8-chunk
  const _Float16* aG = A + (size_t)(m0 + w * 32 + srow) * Kd + slot * 8;
  const _Float16* bG = Bt + (size_t)(n0 + w * 32 + srow) * Kd + slot * 8;
  _Float16* sAw = &sA[w * 2048];
  _Float16* sBw = &sB[w * 2048];

  for (int kt = 0; kt < Kd; kt += 64) {
#pragma unroll
    for (int t = 0; t < 4; ++t) {
      GLD_LDS16(aG + (size_t)t * 8 * Kd + kt, sAw + t * 512);
      GLD_LDS16(bG + (size_t)t * 8 * Kd + kt, sBw + t * 512);
    }
    __syncthreads();
#pragma unroll
    for (int ks = 0; ks < 2; ++ks) {
      half8 af[4], bf[4];
#pragma unroll
      for (int i = 0; i < 4; ++i) {
        int ar = wrow + i * 16 + lr;
        int br = wcol + i * 16 + lr;
        int sl = (((ks << 2) | lq) ^ (lr & 7)) * 8;
        af[i] = *(const half8*)&sA[ar * 64 + sl];
        bf[i] = *(const half8*)&sB[br * 64 + sl];
      }
#pragma unroll
      for (int i = 0; i < 4; ++i)
#pragma unroll
        for (int j = 0; j < 4; ++j) acc[i][j] = mfma16(af[i], bf[j], acc[i][j]);
    }
    __syncthreads();
  }

  if (MODE == 0) {
    // (unused in this round's launch; retained for completeness)
    int which = n0 >> 11;
    float bj[4];
#pragma unroll
    for (int j = 0; j < 4; ++j) bj[j] = bias[n0 + wcol + j * 16 + lr];
    int hh = ((n0 & 2047) + wcol) >> 6;
    if (which == 2) {
#pragma unroll
      for (int j = 0; j < 4; ++j) {
        int dd = j * 16 + lr;
#pragma unroll
        for (int i = 0; i < 4; ++i) {
          int m = m0 + wrow + i * 16 + lq * 4;
          int bb = m >> 11, t = m & 2047;
          half4 h;
#pragma unroll
          for (int r = 0; r < 4; ++r) h[r] = (_Float16)(acc[i][j][r] + bj[j]);
          *(half4*)&Vd[(((size_t)(bb * 32 + hh)) * 64 + dd) * 2048 + t] = h;
        }
      }
    } else {
      _Float16* dst = which ? Kkd : Qd;
      float freq = __expf(-(float)lr * 0.57564627324851148f);
#pragma unroll
      for (int i = 0; i < 4; ++i)
#pragma unroll
        for (int r = 0; r < 4; ++r) {
          int m = m0 + wrow + i * 16 + lq * 4 + r;
          int bb = m >> 11, t = m & 2047;
          float sn, cs;
          __sincosf((float)t * freq, &sn, &cs);
          float x1 = acc[i][0][r] + bj[0];
          float x2 = acc[i][1][r] + bj[1];
          _Float16* row = dst + ((size_t)(bb * 32 + hh) * 2048 + (size_t)t) * 64;
          row[lr]      = (_Float16)(x1 * cs - x2 * sn);
          row[lr + 16] = (_Float16)(x1 * sn + x2 * cs);
          row[lr + 32] = (_Float16)(acc[i][2][r] + bj[2]);
          row[lr + 48] = (_Float16)(acc[i][3][r] + bj[3]);
        }
    }
  } else {
#pragma unroll
    for (int j = 0; j < 4; ++j) {
      int n = n0 + wcol + j * 16 + lr;
      float bj = bias[n];
#pragma unroll
      for (int i = 0; i < 4; ++i)
#pragma unroll
        for (int r = 0; r < 4; ++r) {
          int m = m0 + wrow + i * 16 + lq * 4 + r;
          Co[(size_t)m * Nd + n] = acc[i][j][r] + bj;
        }
    }
  }
}

// ---------------------------------------------------------------- attention
// Flash-style causal attention, S^T formulation + register prefetch +
// PAIRED q-tiles: block (bh, by) runs qt=15-by then qt=by -> every block
// does exactly 17 kv-iterations (uniform work, no imbalance tail).
__global__ __launch_bounds__(256) void attn_kernel(
    const _Float16* __restrict__ Q, const _Float16* __restrict__ Kk,
    const _Float16* __restrict__ Vt, _Float16* __restrict__ O) {
  constexpr int S = 2048;
  int bh = blockIdx.x;
  int by = blockIdx.y;  // 0..7
  int bb = bh >> 5, hh = bh & 31;
  const _Float16* Qb = Q + (size_t)bh * S * 64;
  const _Float16* Kb = Kk + (size_t)bh * S * 64;
  const _Float16* Vb = Vt + (size_t)bh * 64 * S;

  __shared__ __align__(16) _Float16 sK[128 * 72];   // [kv][64+pad], reused as sO
  __shared__ __align__(16) _Float16 sVt[64 * 136];  // [d][128+pad]

  int tid = threadIdx.x, w = tid >> 6, l = tid & 63;
  int lr = l & 15, quad = l >> 4;

  int rk = tid >> 3, ck = (tid & 7) * 8;   // K: 32 rows x 64d per pass
  int rv = tid >> 4, cv = (tid & 15) * 8;  // Vt: 16 rows x 128kv per pass
  const _Float16* Kst = Kb + (size_t)rk * 64 + ck;
  const _Float16* Vst = Vb + (size_t)rv * S + cv;

  int qts[2] = {15 - by, by};
  floatx4 z4 = {0.f, 0.f, 0.f, 0.f};

  for (int h = 0; h < 2; ++h) {
    int qt = qts[h];
    int q0 = qt * 128;

    half8 qf[2][2];  // [qtile][ks]
#pragma unroll
    for (int qtl = 0; qtl < 2; ++qtl)
#pragma unroll
      for (int ks = 0; ks < 2; ++ks) {
        half8 v = *(const half8*)(Qb + (size_t)(q0 + w * 32 + qtl * 16 + lr) * 64 +
                                  ks * 32 + quad * 8);
        qf[qtl][ks] = v * (_Float16)0.18033688f;  // 0.125 * log2(e)
      }

    floatx4 Oa[4][2];
    float m_i[2] = {-1e30f, -1e30f}, l_i[2] = {0.f, 0.f};
#pragma unroll
    for (int dt = 0; dt < 4; ++dt)
#pragma unroll
      for (int qtl = 0; qtl < 2; ++qtl) Oa[dt][qtl] = z4;

    half8 kpre[4], vpre[4];
#pragma unroll
    for (int it = 0; it < 4; ++it) {
      kpre[it] = *(const half8*)(Kst + (size_t)it * 32 * 64);
      vpre[it] = *(const half8*)(Vst + (size_t)it * 16 * S);
    }

    for (int jt = 0; jt <= qt; ++jt) {
#pragma unroll
      for (int it = 0; it < 4; ++it) {
        *(half8*)&sK[(rk + it * 32) * 72 + ck] = kpre[it];
        *(half8*)&sVt[(rv + it * 16) * 136 + cv] = vpre[it];
      }
      if (jt < qt) {
        int kv1 = (jt + 1) * 128;
#pragma unroll
        for (int it = 0; it < 4; ++it) {
          kpre[it] = *(const half8*)(Kst + (size_t)(kv1 + it * 32) * 64);
          vpre[it] = *(const half8*)(Vst + kv1 + (size_t)it * 16 * S);
        }
      }
      __syncthreads();

      floatx4 Sa[2][8];
#pragma unroll
      for (int qtl = 0; qtl < 2; ++qtl)
#pragma unroll
        for (int kvt = 0; kvt < 8; ++kvt) Sa[qtl][kvt] = z4;
      __builtin_amdgcn_s_setprio(1);
#pragma unroll
      for (int ks = 0; ks < 2; ++ks) {
#pragma unroll
        for (int kvt = 0; kvt < 8; ++kvt) {
          half8 kf = *(const half8*)&sK[(kvt * 16 + lr) * 72 + ks * 32 + quad * 8];
          Sa[0][kvt] = mfma16(kf, qf[0][ks], Sa[0][kvt]);
          Sa[1][kvt] = mfma16(kf, qf[1][ks], Sa[1][kvt]);
        }
      }
      __builtin_amdgcn_s_setprio(0);

      if (jt == qt) {
#pragma unroll
        for (int qtl = 0; qtl < 2; ++qtl) {
          int q_loc = w * 32 + qtl * 16 + lr;
#pragma unroll
          for (int kvt = 0; kvt < 8; ++kvt) {
            int kv_base = kvt * 16 + quad * 4;
#pragma unroll
            for (int r = 0; r < 4; ++r)
              if (kv_base + r > q_loc) Sa[qtl][kvt][r] = -1e30f;
          }
        }
      }

#pragma unroll
      for (int qtl = 0; qtl < 2; ++qtl) {
        float mx = Sa[qtl][0][0];
#pragma unroll
        for (int kvt = 0; kvt < 8; ++kvt)
#pragma unroll
          for (int r = 0; r < 4; ++r) mx = fmaxf(mx, Sa[qtl][kvt][r]);
        mx = fmaxf(mx, __shfl_xor(mx, 16));
        mx = fmaxf(mx, __shfl_xor(mx, 32));
        float mnew = fmaxf(m_i[qtl], mx);
        float alpha = __builtin_amdgcn_exp2f(m_i[qtl] - mnew);
        m_i[qtl] = mnew;
        float rs = 0.f;
#pragma unroll
        for (int kvt = 0; kvt < 8; ++kvt)
#pragma unroll
          for (int r = 0; r < 4; ++r) {
            float p = __builtin_amdgcn_exp2f(Sa[qtl][kvt][r] - mnew);
            Sa[qtl][kvt][r] = p;
            rs += p;
          }
        rs += __shfl_xor(rs, 16);
        rs += __shfl_xor(rs, 32);
        l_i[qtl] = l_i[qtl] * alpha + rs;
#pragma unroll
        for (int dt = 0; dt < 4; ++dt) Oa[dt][qtl] *= alpha;
      }

      __builtin_amdgcn_s_setprio(1);
#pragma unroll
      for (int kvt = 0; kvt < 8; ++kvt) {
        half4 vf[4];
#pragma unroll
        for (int dt = 0; dt < 4; ++dt)
          vf[dt] = *(const half4*)&sVt[(dt * 16 + lr) * 136 + kvt * 16 + quad * 4];
        half4 pf[2];
#pragma unroll
        for (int qtl = 0; qtl < 2; ++qtl) {
          pf[qtl][0] = (_Float16)Sa[qtl][kvt][0];
          pf[qtl][1] = (_Float16)Sa[qtl][kvt][1];
          pf[qtl][2] = (_Float16)Sa[qtl][kvt][2];
          pf[qtl][3] = (_Float16)Sa[qtl][kvt][3];
        }
#pragma unroll
        for (int dt = 0; dt < 4; ++dt)
#pragma unroll
          for (int qtl = 0; qtl < 2; ++qtl)
            Oa[dt][qtl] = mfma16k16(vf[dt], pf[qtl], Oa[dt][qtl]);
      }
      __builtin_amdgcn_s_setprio(0);
      __syncthreads();
    }

    float inv0 = 1.0f / l_i[0], inv1 = 1.0f / l_i[1];
#pragma unroll
    for (int dt = 0; dt < 4; ++dt)
#pragma unroll
      for (int qtl = 0; qtl < 2; ++qtl) {
        float inv = qtl ? inv1 : inv0;
        floatx4 o = Oa[dt][qtl];
        half4 hv;
        hv[0] = (_Float16)(o[0] * inv); hv[1] = (_Float16)(o[1] * inv);
        hv[2] = (_Float16)(o[2] * inv); hv[3] = (_Float16)(o[3] * inv);
        *(half4*)&sK[(w * 32 + qtl * 16 + lr) * 72 + dt * 16 + quad * 4] = hv;
      }
    __syncthreads();
#pragma unroll
    for (int it = 0; it < 2; ++it) {
      int row = (tid >> 2) + it * 64;
      int t = q0 + row;
      _Float16* orow = O + ((size_t)(bb * 2048 + t)) * 2048 + hh * 64;
#pragma unroll
      for (int cc = 0; cc < 2; ++cc) {
        int col = (tid & 3) * 16 + cc * 8;
        *(half8*)(orow + col) = *(const half8*)&sK[row * 72 + col];
      }
    }
    __syncthreads();
  }
}

// ---------------------------------------------------------------- launch
extern "C" void kernel_launch(void* const* d_in, const int* in_sizes, int n_in,
                              void* d_out, int out_size, void* d_ws, size_t ws_size,
                              hipStream_t stream) {
  (void)in_sizes; (void)n_in; (void)out_size; (void)ws_size;
  const float* x = (const float*)d_in[0];
  const float* Wqkv = (const float*)d_in[1];
  const float* bqkv = (const float*)d_in[2];
  const float* Wout = (const float*)d_in[3];
  const float* bout = (const float*)d_in[4];
  float* out = (float*)d_out;
  char* ws = (char*)d_ws;

  _Float16* xh    = (_Float16*)(ws + 0);
  _Float16* wqkvt = (_Float16*)(ws + 16777216);
  _Float16* Oh    = (_Float16*)(ws + 16777216);   // overlays wqkvt (dead)
  _Float16* Qh    = (_Float16*)(ws + 41943040);
  _Float16* Kh    = (_Float16*)(ws + 58720256);
  _Float16* Vth   = (_Float16*)(ws + 75497472);   // V^T
  _Float16* woutt = (_Float16*)(ws + 92274688);   // total 96 MB

  cvt_x_kernel<<<4096, 256, 0, stream>>>(x, xh);
  cvt_wt_kernel<<<dim3(96, 32), 256, 0, stream>>>(Wqkv, wqkvt, 2048, 6144);
  cvt_wt_kernel<<<dim3(32, 32), 256, 0, stream>>>(Wout, woutt, 2048, 2048);
  gemm256_kernel<<<dim3(24, 16), 512, 0, stream>>>(xh, wqkvt, bqkv, Qh, Kh, Vth);
  attn_kernel<<<dim3(64, 8), 256, 0, stream>>>(Qh, Kh, Vth, Oh);
  gemm_f16_kernel<1><<<dim3(16, 32), 256, 0, stream>>>(
      Oh, woutt, bout, 2048, 2048, nullptr, nullptr, nullptr, out);
}

// Round 7
// 388.672 us; speedup vs baseline: 1.0287x; 1.0181x over previous
//
#include <hip/hip_runtime.h>

// MHA fused pipeline for MI355X (gfx950), f16 MFMA + fp32 accumulate.
// Round 14:
//  - gemm QKV: 256x192 tile, waves 4Mx2N. Five schedule variants (R8-R13:
//    2-bar, 1-bar/phase, m-pair regs, tile-ahead vmcnt, zero interior
//    barriers) all ~135us / MfmaUtil~32: per-tile 5047cy == LDS-port
//    (2304 read + 512 gld_lds-write) + MFMA (2483) with ~zero overlap --
//    schedule-invariant, so stop chasing overlap and take the structural
//    win: grid 32x16 = 512 blocks = EXACTLY 2 full rounds (was 384 = 1.5
//    rounds, 25% wall half-idle), and the smaller tile cuts the serial sum
//    (reads 160KB: A x2-redundant not x4; MFMA 1862cy; ~4220cy/tile).
//    Predicted ~112us. Epilogue re-derived for 96-col wave span: per-j
//    which/head/d0 classification; rotary pair = (j @ d0==0, j+1).
//  - K-loop keeps R13 single-barrier form (stage t+1 -> nbuf; reads; MFMA;
//    vmcnt(0); barrier).
//
// ws layout (bytes):
//   xh     @ 0          : 4096x2048 f16  (x cast)
//   wqkvt  @ 16777216   : 6144x2048 f16  (Wqkv^T)   [dead after QKV gemm]
//   Oh     @ 16777216   : 4096x2048 f16  (attn out)  [overlays wqkvt]
//   Qh     @ 41943040   : [64 bh][2048][64] f16  (RoPE'd)
//   Kh     @ 58720256   : [64 bh][2048][64] f16  (RoPE'd)
//   Vth    @ 75497472   : [64 bh][64][2048] f16  (V^T)
//   woutt  @ 92274688   : 2048x2048 f16  (Wout^T)
//   total 100663296 B = 96 MB

typedef _Float16 half8 __attribute__((ext_vector_type(8)));
typedef _Float16 half4 __attribute__((ext_vector_type(4)));
typedef float floatx4 __attribute__((ext_vector_type(4)));

#define GLD_LDS16(gp, sp)                                        \
  __builtin_amdgcn_global_load_lds(                              \
      (__attribute__((address_space(1))) void*)(gp),             \
      (__attribute__((address_space(3))) void*)(sp), 16, 0, 0)

__device__ __forceinline__ floatx4 mfma16(half8 a, half8 b, floatx4 c) {
  return __builtin_amdgcn_mfma_f32_16x16x32_f16(a, b, c, 0, 0, 0);
}
__device__ __forceinline__ floatx4 mfma16k16(half4 a, half4 b, floatx4 c) {
  return __builtin_amdgcn_mfma_f32_16x16x16f16(a, b, c, 0, 0, 0);
}

// ---------------------------------------------------------------- cvt_x
__global__ __launch_bounds__(256) void cvt_x_kernel(const float* __restrict__ x,
                                                    _Float16* __restrict__ xh) {
  int idx = blockIdx.x * 256 + threadIdx.x;  // 8 elems each, 8.4M total
  const floatx4* p = (const floatx4*)x + (size_t)idx * 2;
  floatx4 a = p[0], b = p[1];
  half8 o;
#pragma unroll
  for (int j = 0; j < 4; ++j) { o[j] = (_Float16)a[j]; o[4 + j] = (_Float16)b[j]; }
  *((half8*)xh + idx) = o;
}

// ------------------------------------------------------- cvt + transpose W
// W (Kd x Nd) f32 row-major  ->  Wt (Nd x Kd) f16 row-major
__global__ __launch_bounds__(256) void cvt_wt_kernel(const float* __restrict__ W,
                                                     _Float16* __restrict__ Wt,
                                                     int Kd, int Nd) {
  __shared__ float tile[64][65];
  int n0 = blockIdx.x * 64, k0 = blockIdx.y * 64;
  int tid = threadIdx.x;
#pragma unroll
  for (int it = 0; it < 4; ++it) {
    int r = (tid >> 4) + it * 16;   // k-local
    int c = (tid & 15) * 4;         // n-local
    floatx4 v = *(const floatx4*)(W + (size_t)(k0 + r) * Nd + n0 + c);
    tile[r][c + 0] = v[0]; tile[r][c + 1] = v[1];
    tile[r][c + 2] = v[2]; tile[r][c + 3] = v[3];
  }
  __syncthreads();
#pragma unroll
  for (int it = 0; it < 2; ++it) {
    int r = (tid >> 3) + it * 32;   // n-local
    int c = (tid & 7) * 8;          // k-local
    half8 o;
#pragma unroll
    for (int j = 0; j < 8; ++j) o[j] = (_Float16)tile[c + j][r];
    *(half8*)(Wt + (size_t)(n0 + r) * Kd + k0 + c) = o;
  }
}

// --------------------------------------------- 256x192 1-barrier GEMM (QKV)
// C(256x192) = A(4096x2048) @ Bt(6144x2048)^T + bias, QKV epilogue.
//
// 8 waves = 4M x 2N: wr = w>>1 owns rows wr*64..+64; wc = w&1 owns cols
// wc*96..+96 (6 n-tiles of 16). Grid 32x16 = 512 blocks = 2 full rounds.
// LDS: sA [2][256*64], sB [2][192*64] f16 = 112 KiB, 1 block/CU.
// Per-row XOR chunk swizzle via pre-swizzled GLOBAL source chunk
// (l&7)^(l>>3); LDS destination linear (global_load_lds constraint).
// Fragment read slot: chunk (ks*4+quad) ^ (row&7).
//
// Per tile t: STAGE t+1 -> nbuf (A 4 + B 3 gld_lds per wave); read bf (12
// b128) + af (8 b128); 48 MFMA (setprio); vmcnt(0); s_barrier.
// Hazards: buf published by prev tile's vmcnt+barrier; nbuf stage issued
// after the barrier that ended its last reader tile; skew bounded.
__global__ __launch_bounds__(512, 2) void gemm_qkv_kernel(
    const _Float16* __restrict__ A, const _Float16* __restrict__ Bt,
    const float* __restrict__ bias,
    _Float16* __restrict__ Qd, _Float16* __restrict__ Kkd,
    _Float16* __restrict__ Vd) {
  __shared__ __align__(16) _Float16 sA[2][16384];   // 256 x 64
  __shared__ __align__(16) _Float16 sB[2][12288];   // 192 x 64
  constexpr int KD = 2048;
  constexpr int NT = KD / 64;  // 32 K-tiles

  int tid = threadIdx.x, w = tid >> 6, l = tid & 63;
  int lr = l & 15, quad = l >> 4;
  int wr = w >> 1, wc = w & 1;
  int m0 = blockIdx.y * 256, n0 = blockIdx.x * 192;

  // fragment-read swizzled column offsets (f16 units), loop-invariant
  int csw0 = ((quad) ^ (lr & 7)) * 8;
  int csw1 = ((quad + 4) ^ (lr & 7)) * 8;

  // staging: wave w covers A rows w*32..+32 (4 instr) and B rows w*24..+24
  // (3 instr); lane l -> row base+(l>>3), global chunk (l&7)^(l>>3).
  const _Float16* pA[4];
  const _Float16* pB[3];
  {
    int rl = l >> 3;
    int cs = ((l & 7) ^ rl) * 8;
#pragma unroll
    for (int jj = 0; jj < 4; ++jj)
      pA[jj] = A + (size_t)(m0 + w * 32 + jj * 8 + rl) * KD + cs;
#pragma unroll
    for (int jj = 0; jj < 3; ++jj)
      pB[jj] = Bt + (size_t)(n0 + w * 24 + jj * 8 + rl) * KD + cs;
  }

#define STAGE_ALL(BUF, KT)                                                   \
  _Pragma("unroll") for (int jj = 0; jj < 4; ++jj)                           \
    GLD_LDS16(pA[jj] + (KT), &sA[BUF][(w * 32 + jj * 8) * 64]);              \
  _Pragma("unroll") for (int jj = 0; jj < 3; ++jj)                           \
    GLD_LDS16(pB[jj] + (KT), &sB[BUF][(w * 24 + jj * 8) * 64]);

  floatx4 z4 = {0.f, 0.f, 0.f, 0.f};
  floatx4 acc[4][6];
#pragma unroll
  for (int i = 0; i < 4; ++i)
#pragma unroll
    for (int j = 0; j < 6; ++j) acc[i][j] = z4;

  // prologue: tile0 -> buf0, drain, barrier.
  STAGE_ALL(0, 0);
  asm volatile("s_waitcnt vmcnt(0)" ::: "memory");
  __builtin_amdgcn_s_barrier();

  half8 af[4][2], bf[6][2];
#pragma unroll 2
  for (int t = 0; t < NT; ++t) {
    int buf = t & 1, nbuf = buf ^ 1;
    if (t + 1 < NT) { STAGE_ALL(nbuf, (t + 1) * 64); }
    // fragment reads (this tile)
#pragma unroll
    for (int j = 0; j < 6; ++j) {
      int row_ = wc * 96 + j * 16 + lr;
      bf[j][0] = *(const half8*)&sB[buf][row_ * 64 + csw0];
      bf[j][1] = *(const half8*)&sB[buf][row_ * 64 + csw1];
    }
#pragma unroll
    for (int i = 0; i < 4; ++i) {
      int row_ = wr * 64 + i * 16 + lr;
      af[i][0] = *(const half8*)&sA[buf][row_ * 64 + csw0];
      af[i][1] = *(const half8*)&sA[buf][row_ * 64 + csw1];
    }
    __builtin_amdgcn_s_setprio(1);
#pragma unroll
    for (int j = 0; j < 6; ++j)
#pragma unroll
      for (int ks = 0; ks < 2; ++ks)
#pragma unroll
        for (int i = 0; i < 4; ++i)
          acc[i][j] = mfma16(af[i][ks], bf[j][ks], acc[i][j]);
    __builtin_amdgcn_s_setprio(0);
    asm volatile("s_waitcnt vmcnt(0)" ::: "memory");
    __builtin_amdgcn_s_barrier();
  }

  // ---- epilogue. C/D layout: col = lane&15, row = quad*4 + r.
  // Lane's j-tile j -> global col cg = n0 + wc*96 + j*16 + lr.
  // which = cg>>11 (0:q 1:k 2:v), head hh = (cg&2047)>>6, d0 = (cg-lr)&63.
  // Rotary pairs: tiles with d0==0 pair with j+1 (d0==16), always in-wave,
  // never straddling head/qkv boundaries (64-aligned). d0>=32: passthrough.
  float bj[6];
#pragma unroll
  for (int j = 0; j < 6; ++j) bj[j] = bias[n0 + wc * 96 + j * 16 + lr];
  float freq = __expf(-(float)lr * 0.57564627324851148f);  // 10000^(-lr/16)
#pragma unroll
  for (int j = 0; j < 6; ++j) {
    int cb = wc * 96 + j * 16;
    int cg = n0 + cb;
    int which = cg >> 11;
    int d0 = cb & 63;  // n0 is 64-aligned (192*bx)
    int hh = (cg & 2047) >> 6;
    if (which == 2) {
      // V^T: Vd[bh][d=d0+lr][t..t+3]
      int dd = d0 + lr;
#pragma unroll
      for (int i = 0; i < 4; ++i) {
        int m = m0 + wr * 64 + i * 16 + quad * 4;
        int bb = m >> 11, tt = m & 2047;
        half4 h;
#pragma unroll
        for (int r = 0; r < 4; ++r) h[r] = (_Float16)(acc[i][j][r] + bj[j]);
        *(half4*)&Vd[(((size_t)(bb * 32 + hh)) * 64 + dd) * 2048 + tt] = h;
      }
    } else if (d0 == 0) {
      // rotary pair (this tile = x1/d=lr, partner j+1 = x2/d=lr+16)
      _Float16* dst = which ? Kkd : Qd;
#pragma unroll
      for (int i = 0; i < 4; ++i)
#pragma unroll
        for (int r = 0; r < 4; ++r) {
          int m = m0 + wr * 64 + i * 16 + quad * 4 + r;
          int bb = m >> 11, tt = m & 2047;
          float sn, cs2;
          __sincosf((float)tt * freq, &sn, &cs2);
          float x1 = acc[i][j][r] + bj[j];
          float x2 = acc[i][j + 1][r] + bj[j + 1];
          _Float16* row = dst + ((size_t)(bb * 32 + hh) * 2048 + (size_t)tt) * 64;
          row[lr] = (_Float16)(x1 * cs2 - x2 * sn);
          row[lr + 16] = (_Float16)(x1 * sn + x2 * cs2);
        }
    } else if (d0 >= 32) {
      // passthrough d = d0 + lr
      _Float16* dst = which ? Kkd : Qd;
#pragma unroll
      for (int i = 0; i < 4; ++i)
#pragma unroll
        for (int r = 0; r < 4; ++r) {
          int m = m0 + wr * 64 + i * 16 + quad * 4 + r;
          int bb = m >> 11, tt = m & 2047;
          _Float16* row = dst + ((size_t)(bb * 32 + hh) * 2048 + (size_t)tt) * 64;
          row[d0 + lr] = (_Float16)(acc[i][j][r] + bj[j]);
        }
    }
    // d0==16 && which<2: written by the d0==0 partner tile.
  }
#undef STAGE_ALL
}

// ---------------------------------------------------------------- GEMM 128^2
// (kept for the out-projection.)
template <int MODE>
__global__ __launch_bounds__(256) void gemm_f16_kernel(
    const _Float16* __restrict__ A, const _Float16* __restrict__ Bt,
    const float* __restrict__ bias, int Kd, int Nd,
    _Float16* __restrict__ Qd, _Float16* __restrict__ Kkd,
    _Float16* __restrict__ Vd, float* __restrict__ Co) {
  __shared__ __align__(16) _Float16 sA[128 * 64];
  __shared__ __align__(16) _Float16 sB[128 * 64];
  int tid = threadIdx.x, w = tid >> 6, l = tid & 63;
  int lr = l & 15, lq = l >> 4;
  int m0 = blockIdx.y * 128, n0 = blockIdx.x * 128;
  int wrow = (w >> 1) * 64, wcol = (w & 1) * 64;

  floatx4 z4 = {0.f, 0.f, 0.f, 0.f};
  floatx4 acc[4][4];
#pragma unroll
  for (int i = 0; i < 4; ++i)
#pragma unroll
    for (int j = 0; j < 4; ++j) acc[i][j] = z4;

  int srow = l >> 3;              // row within 8-row chunk
  int slot = (l & 7) ^ srow;      // XOR-swizzled global k8-chunk
  const _Float16* aG = A + (size_t)(m0 + w * 32 + srow) * Kd + slot * 8;
  const _Float16* bG = Bt + (size_t)(n0 + w * 32 + srow) * Kd + slot * 8;
  _Float16* sAw = &sA[w * 2048];
  _Float16* sBw = &sB[w * 2048];

  for (int kt = 0; kt < Kd; kt += 64) {
#pragma unroll
    for (int t = 0; t < 4; ++t) {
      GLD_LDS16(aG + (size_t)t * 8 * Kd + kt, sAw + t * 512);
      GLD_LDS16(bG + (size_t)t * 8 * Kd + kt, sBw + t * 512);
    }
    __syncthreads();
#pragma unroll
    for (int ks = 0; ks < 2; ++ks) {
      half8 af[4], bf[4];
#pragma unroll
      for (int i = 0; i < 4; ++i) {
        int ar = wrow + i * 16 + lr;
        int br = wcol + i * 16 + lr;
        int sl = (((ks << 2) | lq) ^ (lr & 7)) * 8;
        af[i] = *(const half8*)&sA[ar * 64 + sl];
        bf[i] = *(const half8*)&sB[br * 64 + sl];
      }
#pragma unroll
      for (int i = 0; i < 4; ++i)
#pragma unroll
        for (int j = 0; j < 4; ++j) acc[i][j] = mfma16(af[i], bf[j], acc[i][j]);
    }
    __syncthreads();
  }

  if (MODE == 0) {
    // (unused in this round's launch; retained for completeness)
    int which = n0 >> 11;
    float bj[4];
#pragma unroll
    for (int j = 0; j < 4; ++j) bj[j] = bias[n0 + wcol + j * 16 + lr];
    int hh = ((n0 & 2047) + wcol) >> 6;
    if (which == 2) {
#pragma unroll
      for (int j = 0; j < 4; ++j) {
        int dd = j * 16 + lr;
#pragma unroll
        for (int i = 0; i < 4; ++i) {
          int m = m0 + wrow + i * 16 + lq * 4;
          int bb = m >> 11, t = m & 2047;
          half4 h;
#pragma unroll
          for (int r = 0; r < 4; ++r) h[r] = (_Float16)(acc[i][j][r] + bj[j]);
          *(half4*)&Vd[(((size_t)(bb * 32 + hh)) * 64 + dd) * 2048 + t] = h;
        }
      }
    } else {
      _Float16* dst = which ? Kkd : Qd;
      float freq = __expf(-(float)lr * 0.57564627324851148f);
#pragma unroll
      for (int i = 0; i < 4; ++i)
#pragma unroll
        for (int r = 0; r < 4; ++r) {
          int m = m0 + wrow + i * 16 + lq * 4 + r;
          int bb = m >> 11, t = m & 2047;
          float sn, cs;
          __sincosf((float)t * freq, &sn, &cs);
          float x1 = acc[i][0][r] + bj[0];
          float x2 = acc[i][1][r] + bj[1];
          _Float16* row = dst + ((size_t)(bb * 32 + hh) * 2048 + (size_t)t) * 64;
          row[lr]      = (_Float16)(x1 * cs - x2 * sn);
          row[lr + 16] = (_Float16)(x1 * sn + x2 * cs);
          row[lr + 32] = (_Float16)(acc[i][2][r] + bj[2]);
          row[lr + 48] = (_Float16)(acc[i][3][r] + bj[3]);
        }
    }
  } else {
#pragma unroll
    for (int j = 0; j < 4; ++j) {
      int n = n0 + wcol + j * 16 + lr;
      float bj = bias[n];
#pragma unroll
      for (int i = 0; i < 4; ++i)
#pragma unroll
        for (int r = 0; r < 4; ++r) {
          int m = m0 + wrow + i * 16 + lq * 4 + r;
          Co[(size_t)m * Nd + n] = acc[i][j][r] + bj;
        }
    }
  }
}

// ---------------------------------------------------------------- attention
// Flash-style causal attention, S^T formulation + register prefetch +
// PAIRED q-tiles: block (bh, by) runs qt=15-by then qt=by -> every block
// does exactly 17 kv-iterations (uniform work, no imbalance tail).
__global__ __launch_bounds__(256) void attn_kernel(
    const _Float16* __restrict__ Q, const _Float16* __restrict__ Kk,
    const _Float16* __restrict__ Vt, _Float16* __restrict__ O) {
  constexpr int S = 2048;
  int bh = blockIdx.x;
  int by = blockIdx.y;  // 0..7
  int bb = bh >> 5, hh = bh & 31;
  const _Float16* Qb = Q + (size_t)bh * S * 64;
  const _Float16* Kb = Kk + (size_t)bh * S * 64;
  const _Float16* Vb = Vt + (size_t)bh * 64 * S;

  __shared__ __align__(16) _Float16 sK[128 * 72];   // [kv][64+pad], reused as sO
  __shared__ __align__(16) _Float16 sVt[64 * 136];  // [d][128+pad]

  int tid = threadIdx.x, w = tid >> 6, l = tid & 63;
  int lr = l & 15, quad = l >> 4;

  int rk = tid >> 3, ck = (tid & 7) * 8;   // K: 32 rows x 64d per pass
  int rv = tid >> 4, cv = (tid & 15) * 8;  // Vt: 16 rows x 128kv per pass
  const _Float16* Kst = Kb + (size_t)rk * 64 + ck;
  const _Float16* Vst = Vb + (size_t)rv * S + cv;

  int qts[2] = {15 - by, by};
  floatx4 z4 = {0.f, 0.f, 0.f, 0.f};

  for (int h = 0; h < 2; ++h) {
    int qt = qts[h];
    int q0 = qt * 128;

    half8 qf[2][2];  // [qtile][ks]
#pragma unroll
    for (int qtl = 0; qtl < 2; ++qtl)
#pragma unroll
      for (int ks = 0; ks < 2; ++ks) {
        half8 v = *(const half8*)(Qb + (size_t)(q0 + w * 32 + qtl * 16 + lr) * 64 +
                                  ks * 32 + quad * 8);
        qf[qtl][ks] = v * (_Float16)0.18033688f;  // 0.125 * log2(e)
      }

    floatx4 Oa[4][2];
    float m_i[2] = {-1e30f, -1e30f}, l_i[2] = {0.f, 0.f};
#pragma unroll
    for (int dt = 0; dt < 4; ++dt)
#pragma unroll
      for (int qtl = 0; qtl < 2; ++qtl) Oa[dt][qtl] = z4;

    half8 kpre[4], vpre[4];
#pragma unroll
    for (int it = 0; it < 4; ++it) {
      kpre[it] = *(const half8*)(Kst + (size_t)it * 32 * 64);
      vpre[it] = *(const half8*)(Vst + (size_t)it * 16 * S);
    }

    for (int jt = 0; jt <= qt; ++jt) {
#pragma unroll
      for (int it = 0; it < 4; ++it) {
        *(half8*)&sK[(rk + it * 32) * 72 + ck] = kpre[it];
        *(half8*)&sVt[(rv + it * 16) * 136 + cv] = vpre[it];
      }
      if (jt < qt) {
        int kv1 = (jt + 1) * 128;
#pragma unroll
        for (int it = 0; it < 4; ++it) {
          kpre[it] = *(const half8*)(Kst + (size_t)(kv1 + it * 32) * 64);
          vpre[it] = *(const half8*)(Vst + kv1 + (size_t)it * 16 * S);
        }
      }
      __syncthreads();

      floatx4 Sa[2][8];
#pragma unroll
      for (int qtl = 0; qtl < 2; ++qtl)
#pragma unroll
        for (int kvt = 0; kvt < 8; ++kvt) Sa[qtl][kvt] = z4;
      __builtin_amdgcn_s_setprio(1);
#pragma unroll
      for (int ks = 0; ks < 2; ++ks) {
#pragma unroll
        for (int kvt = 0; kvt < 8; ++kvt) {
          half8 kf = *(const half8*)&sK[(kvt * 16 + lr) * 72 + ks * 32 + quad * 8];
          Sa[0][kvt] = mfma16(kf, qf[0][ks], Sa[0][kvt]);
          Sa[1][kvt] = mfma16(kf, qf[1][ks], Sa[1][kvt]);
        }
      }
      __builtin_amdgcn_s_setprio(0);

      if (jt == qt) {
#pragma unroll
        for (int qtl = 0; qtl < 2; ++qtl) {
          int q_loc = w * 32 + qtl * 16 + lr;
#pragma unroll
          for (int kvt = 0; kvt < 8; ++kvt) {
            int kv_base = kvt * 16 + quad * 4;
#pragma unroll
            for (int r = 0; r < 4; ++r)
              if (kv_base + r > q_loc) Sa[qtl][kvt][r] = -1e30f;
          }
        }
      }

#pragma unroll
      for (int qtl = 0; qtl < 2; ++qtl) {
        float mx = Sa[qtl][0][0];
#pragma unroll
        for (int kvt = 0; kvt < 8; ++kvt)
#pragma unroll
          for (int r = 0; r < 4; ++r) mx = fmaxf(mx, Sa[qtl][kvt][r]);
        mx = fmaxf(mx, __shfl_xor(mx, 16));
        mx = fmaxf(mx, __shfl_xor(mx, 32));
        float mnew = fmaxf(m_i[qtl], mx);
        float alpha = __builtin_amdgcn_exp2f(m_i[qtl] - mnew);
        m_i[qtl] = mnew;
        float rs = 0.f;
#pragma unroll
        for (int kvt = 0; kvt < 8; ++kvt)
#pragma unroll
          for (int r = 0; r < 4; ++r) {
            float p = __builtin_amdgcn_exp2f(Sa[qtl][kvt][r] - mnew);
            Sa[qtl][kvt][r] = p;
            rs += p;
          }
        rs += __shfl_xor(rs, 16);
        rs += __shfl_xor(rs, 32);
        l_i[qtl] = l_i[qtl] * alpha + rs;
#pragma unroll
        for (int dt = 0; dt < 4; ++dt) Oa[dt][qtl] *= alpha;
      }

      __builtin_amdgcn_s_setprio(1);
#pragma unroll
      for (int kvt = 0; kvt < 8; ++kvt) {
        half4 vf[4];
#pragma unroll
        for (int dt = 0; dt < 4; ++dt)
          vf[dt] = *(const half4*)&sVt[(dt * 16 + lr) * 136 + kvt * 16 + quad * 4];
        half4 pf[2];
#pragma unroll
        for (int qtl = 0; qtl < 2; ++qtl) {
          pf[qtl][0] = (_Float16)Sa[qtl][kvt][0];
          pf[qtl][1] = (_Float16)Sa[qtl][kvt][1];
          pf[qtl][2] = (_Float16)Sa[qtl][kvt][2];
          pf[qtl][3] = (_Float16)Sa[qtl][kvt][3];
        }
#pragma unroll
        for (int dt = 0; dt < 4; ++dt)
#pragma unroll
          for (int qtl = 0; qtl < 2; ++qtl)
            Oa[dt][qtl] = mfma16k16(vf[dt], pf[qtl], Oa[dt][qtl]);
      }
      __builtin_amdgcn_s_setprio(0);
      __syncthreads();
    }

    float inv0 = 1.0f / l_i[0], inv1 = 1.0f / l_i[1];
#pragma unroll
    for (int dt = 0; dt < 4; ++dt)
#pragma unroll
      for (int qtl = 0; qtl < 2; ++qtl) {
        float inv = qtl ? inv1 : inv0;
        floatx4 o = Oa[dt][qtl];
        half4 hv;
        hv[0] = (_Float16)(o[0] * inv); hv[1] = (_Float16)(o[1] * inv);
        hv[2] = (_Float16)(o[2] * inv); hv[3] = (_Float16)(o[3] * inv);
        *(half4*)&sK[(w * 32 + qtl * 16 + lr) * 72 + dt * 16 + quad * 4] = hv;
      }
    __syncthreads();
#pragma unroll
    for (int it = 0; it < 2; ++it) {
      int row = (tid >> 2) + it * 64;
      int t = q0 + row;
      _Float16* orow = O + ((size_t)(bb * 2048 + t)) * 2048 + hh * 64;
#pragma unroll
      for (int cc = 0; cc < 2; ++cc) {
        int col = (tid & 3) * 16 + cc * 8;
        *(half8*)(orow + col) = *(const half8*)&sK[row * 72 + col];
      }
    }
    __syncthreads();
  }
}

// ---------------------------------------------------------------- launch
extern "C" void kernel_launch(void* const* d_in, const int* in_sizes, int n_in,
                              void* d_out, int out_size, void* d_ws, size_t ws_size,
                              hipStream_t stream) {
  (void)in_sizes; (void)n_in; (void)out_size; (void)ws_size;
  const float* x = (const float*)d_in[0];
  const float* Wqkv = (const float*)d_in[1];
  const float* bqkv = (const float*)d_in[2];
  const float* Wout = (const float*)d_in[3];
  const float* bout = (const float*)d_in[4];
  float* out = (float*)d_out;
  char* ws = (char*)d_ws;

  _Float16* xh    = (_Float16*)(ws + 0);
  _Float16* wqkvt = (_Float16*)(ws + 16777216);
  _Float16* Oh    = (_Float16*)(ws + 16777216);   // overlays wqkvt (dead)
  _Float16* Qh    = (_Float16*)(ws + 41943040);
  _Float16* Kh    = (_Float16*)(ws + 58720256);
  _Float16* Vth   = (_Float16*)(ws + 75497472);   // V^T
  _Float16* woutt = (_Float16*)(ws + 92274688);   // total 96 MB

  cvt_x_kernel<<<4096, 256, 0, stream>>>(x, xh);
  cvt_wt_kernel<<<dim3(96, 32), 256, 0, stream>>>(Wqkv, wqkvt, 2048, 6144);
  cvt_wt_kernel<<<dim3(32, 32), 256, 0, stream>>>(Wout, woutt, 2048, 2048);
  gemm_qkv_kernel<<<dim3(32, 16), 512, 0, stream>>>(xh, wqkvt, bqkv, Qh, Kh, Vth);
  attn_kernel<<<dim3(64, 8), 256, 0, stream>>>(Qh, Kh, Vth, Oh);
  gemm_f16_kernel<1><<<dim3(16, 32), 256, 0, stream>>>(
      Oh, woutt, bout, 2048, 2048, nullptr, nullptr, nullptr, out);
}